// Round 5
// baseline (311.925 us; speedup 1.0000x reference)
//
#include <hip/hip_runtime.h>
#include <math.h>

// Problem constants: T=4096, N=16, D=512.
#define T_   4096
#define D_   512
#define N_   16
#define ND_  (N_*D_)       // 8192 chains

// Primary segmentation: 128 segments of 32 steps (vec4 kernels).
// 1024 blocks / 4096 waves for K5 -> 4 waves/SIMD (2x the in-flight bytes
// of every prior K5 variant, which all sat at 2 waves/SIMD and ~2.7 TB/s).
#define S_    128
#define L_    32
#define SND_  (S_*ND_)     // 1,048,576 -> 3 arrays = 12 MiB workspace
#define ND4_  (ND_/4)      // 2048 float4-chains
#define SND4_ (S_*ND4_)    // 262,144 vec4 threads

// Fallback segmentation (round-1 verified): 32 segments of 128, scalar.
#define SB_   32
#define LB_   128
#define SNDB_ (SB_*ND_)    // 262,144 -> 3 MiB workspace

typedef float f4 __attribute__((ext_vector_type(4)));

__device__ __forceinline__ f4 vfma(f4 a, f4 b, f4 c) {
    f4 r;
    r.x = fmaf(a.x, b.x, c.x);
    r.y = fmaf(a.y, b.y, c.y);
    r.z = fmaf(a.z, b.z, c.z);
    r.w = fmaf(a.w, b.w, c.w);
    return r;
}

// c^(2^K) by K squarings.
template <int K>
__device__ __forceinline__ float pow2k(float c) {
    float r = c;
    #pragma unroll
    for (int i = 0; i < K; ++i) r *= r;
    return r;
}

// ---------------------------------------------------------------------------
// K1 (vec4): per (s,n,d4) one pass over its segment with zero-init states.
//   P  = particular ha at segment end     (p' = p + a*(x-p))
//   Q0 = particular hv at segment end     (q' = c*(q + a*e^2), e = x-p)
//   S1 = sum of e_t
// ---------------------------------------------------------------------------
__global__ __launch_bounds__(256) void k1_seg_v4(const f4* __restrict__ x4,
                                                 const f4* __restrict__ alpha4,
                                                 f4* __restrict__ P4,
                                                 f4* __restrict__ Q04,
                                                 f4* __restrict__ S14) {
    int bid  = blockIdx.x;
    int obid = (bid & 7) * (SND4_ / 256 / 8) + (bid >> 3);   // XCD swizzle (reads)
    int gid  = obid * 256 + threadIdx.x;       // [0, SND4_)
    int nd4  = gid & (ND4_ - 1);
    int s    = gid >> 11;                      // / ND4_
    f4 a = alpha4[nd4];
    f4 c = 1.0f - a;
    f4 p = 0.0f, q = 0.0f, s1 = 0.0f;
    const f4* xp = x4 + (size_t)s * L_ * (D_ / 4) + (gid & (D_ / 4 - 1));
    #pragma unroll 8
    for (int t = 0; t < L_; ++t) {
        f4 xv = xp[(size_t)t * (D_ / 4)];
        f4 e  = xv - p;
        q  = c * vfma(a, e * e, q);
        p  = vfma(a, e, p);
        s1 += e;
    }
    P4[gid]  = p;
    Q04[gid] = q;
    S14[gid] = s1;
}

// ---------------------------------------------------------------------------
// K2: per (n,d) scan across segments for BOTH ha and hv; overwrites P with
// segment-start ha and Q0 with segment-start hv; writes finals.
//   hv_L = cL*hv0 + Q0 - 2*a*cL*S1*ha0 + cL*(1-cL)*ha0^2 ;  ha_L = cL*ha0 + P
// ---------------------------------------------------------------------------
template <int SS, int LOG2L>
__global__ __launch_bounds__(256) void k2_prefix(const float* __restrict__ h_a,
                                                 const float* __restrict__ h_s,
                                                 const float* __restrict__ alpha,
                                                 float* __restrict__ P,    // -> haStart
                                                 float* __restrict__ Q0,   // -> hvStart
                                                 const float* __restrict__ S1,
                                                 float* __restrict__ out_ha_final,
                                                 float* __restrict__ out_hs_final) {
    int nd   = blockIdx.x * 256 + threadIdx.x;    // [0, ND_)
    float a  = alpha[nd];
    float c  = 1.0f - a;
    float cL = pow2k<LOG2L>(c);
    float k1 = 2.0f * a * cL;
    float k2 = cL * (1.0f - cL);
    float H  = h_a[nd];
    float hs = h_s[nd];
    float V  = hs * hs;
    #pragma unroll 4
    for (int s = 0; s < SS; ++s) {
        size_t i = (size_t)s * ND_ + nd;
        float p  = P[i];
        float q  = Q0[i];
        float s1 = S1[i];
        P[i]  = H;
        Q0[i] = V;
        float Vn = cL * V + q - k1 * s1 * H + k2 * H * H;
        V = fmaxf(Vn, 0.0f);                      // guard cancellation (hv >= 0)
        H = fmaf(cL, H, p);
    }
    out_ha_final[nd] = H;
    out_hs_final[nd] = sqrtf(V);
}

// ---------------------------------------------------------------------------
// K5 (vec4, plain stores, NO swizzle, 4 waves/SIMD): per (s,n,d4) thread runs
// the exact reference recurrence for 4 consecutive d. Differences vs R4:
//  - 1024 blocks (S=128) -> 4096 waves: 2x in-flight store bytes.
//  - blockIdx used directly: co-resident blocks write ADJACENT output regions
//    (dense advancing front, like the 6.45 TB/s harness fill) instead of the
//    XCD swizzle's 33MB-apart scatter.
// ---------------------------------------------------------------------------
__global__ __launch_bounds__(256) void k5_v4(const f4* __restrict__ x4,
                                             const f4* __restrict__ alpha4,
                                             const f4* __restrict__ haStart4,
                                             const f4* __restrict__ hvStart4,
                                             f4* __restrict__ out4) {
    int gid  = blockIdx.x * 256 + threadIdx.x; // [0, SND4_)
    int d4   = gid & (D_ / 4 - 1);             // [0,128)
    int n    = (gid >> 7) & (N_ - 1);
    int nd4  = gid & (ND4_ - 1);
    int s    = gid >> 11;
    f4 a  = alpha4[nd4];
    f4 c  = 1.0f - a;
    f4 ha = haStart4[gid];
    f4 hv = hvStart4[gid];
    const f4* xp = x4 + (size_t)s * L_ * (D_ / 4) + d4;
    f4* oa = out4 + (size_t)s * L_ * (2 * ND4_) + (size_t)n * (D_ / 4) + d4;
    #pragma unroll 4
    for (int t = 0; t < L_; ++t) {
        f4 xv = xp[(size_t)t * (D_ / 4)];
        f4 dd = xv - ha;
        hv = c * vfma(a, dd * dd, hv);
        ha = vfma(a, dd, ha);
        f4 sq;
        sq.x = __builtin_amdgcn_sqrtf(hv.x);
        sq.y = __builtin_amdgcn_sqrtf(hv.y);
        sq.z = __builtin_amdgcn_sqrtf(hv.z);
        sq.w = __builtin_amdgcn_sqrtf(hv.w);
        oa[(size_t)t * 2 * ND4_]        = ha;   // plain store
        oa[(size_t)t * 2 * ND4_ + ND4_] = sq;   // plain store
    }
}

// ---------------------------------------------------------------------------
// Fallback (round-1 verified): scalar coarse pipeline, 3 MiB workspace.
// ---------------------------------------------------------------------------
__global__ __launch_bounds__(256) void k1_fb(const float* __restrict__ x,
                                             const float* __restrict__ alpha,
                                             float* __restrict__ P,
                                             float* __restrict__ Q0,
                                             float* __restrict__ S1) {
    int bid  = blockIdx.x;
    int obid = (bid & 7) * 128 + (bid >> 3);
    int gid  = obid * 256 + threadIdx.x;
    int d    = gid & (D_ - 1);
    int nd   = gid & (ND_ - 1);
    int s    = gid >> 13;
    float a  = alpha[nd];
    float c  = 1.0f - a;
    float p = 0.0f, q = 0.0f, s1 = 0.0f;
    const float* xp = x + (size_t)s * LB_ * D_ + d;
    #pragma unroll 8
    for (int t = 0; t < LB_; ++t) {
        float xv = xp[(size_t)t * D_];
        float e  = xv - p;
        q  = c * fmaf(a, e * e, q);
        p  = fmaf(a, e, p);
        s1 += e;
    }
    P[gid]  = p;
    Q0[gid] = q;
    S1[gid] = s1;
}

__global__ __launch_bounds__(256) void k5_fb(const float* __restrict__ x,
                                             const float* __restrict__ alpha,
                                             const float* __restrict__ haStart,
                                             const float* __restrict__ hvStart,
                                             float* __restrict__ out) {
    int bid  = blockIdx.x;
    int obid = (bid & 7) * 128 + (bid >> 3);
    int gid  = obid * 256 + threadIdx.x;
    int d    = gid & (D_ - 1);
    int n    = (gid >> 9) & (N_ - 1);
    int nd   = gid & (ND_ - 1);
    int s    = gid >> 13;
    float a  = alpha[nd];
    float c  = 1.0f - a;
    float ha = haStart[gid];
    float hv = hvStart[gid];
    const float* xp = x + (size_t)s * LB_ * D_ + d;
    float* oa = out + (size_t)s * LB_ * 2 * ND_ + (size_t)n * D_ + d;
    float* os = oa + ND_;
    #pragma unroll 4
    for (int t = 0; t < LB_; ++t) {
        float xv = xp[(size_t)t * D_];
        float dd = xv - ha;
        hv = c * fmaf(a, dd * dd, hv);
        ha = fmaf(a, dd, ha);
        oa[(size_t)t * 2 * ND_] = ha;
        os[(size_t)t * 2 * ND_] = __builtin_amdgcn_sqrtf(hv);
    }
}

extern "C" void kernel_launch(void* const* d_in, const int* in_sizes, int n_in,
                              void* d_out, int out_size, void* d_ws, size_t ws_size,
                              hipStream_t stream) {
    const float* x     = (const float*)d_in[0];   // [T, D]
    const float* h_a   = (const float*)d_in[1];   // [N, D]
    const float* h_s   = (const float*)d_in[2];   // [N, D]
    const float* alpha = (const float*)d_in[3];   // [N, D]
    float* out = (float*)d_out;                   // [T, 2N, D] ++ ha_N ++ sqrt(hv_N)

    float* out_ha_final = out + (size_t)T_ * 2 * ND_;   // [N, D]
    float* out_hs_final = out_ha_final + ND_;           // [N, D]

    dim3 b256(256);
    float* ws = (float*)d_ws;

    if (ws_size >= (size_t)3 * SND_ * sizeof(float)) {
        // Primary: S=128/L=32, vec4, plain stores, no store-side swizzle.
        float* P  = ws;                            // [S, N, D] -> haStart
        float* Q0 = ws + (size_t)SND_;             // [S, N, D] -> hvStart
        float* S1 = ws + 2 * (size_t)SND_;         // [S, N, D]
        k1_seg_v4<<<dim3(SND4_ / 256), b256, 0, stream>>>(
            (const f4*)x, (const f4*)alpha, (f4*)P, (f4*)Q0, (f4*)S1);
        k2_prefix<S_, 5><<<dim3(ND_ / 256), b256, 0, stream>>>(
            h_a, h_s, alpha, P, Q0, S1, out_ha_final, out_hs_final);
        k5_v4<<<dim3(SND4_ / 256), b256, 0, stream>>>(
            (const f4*)x, (const f4*)alpha, (const f4*)P, (const f4*)Q0, (f4*)out);
    } else {
        // Fallback: round-1 verified pipeline (3 MiB workspace).
        float* P  = ws;
        float* Q0 = ws + (size_t)SNDB_;
        float* S1 = ws + 2 * (size_t)SNDB_;
        k1_fb<<<dim3(SNDB_ / 256), b256, 0, stream>>>(x, alpha, P, Q0, S1);
        k2_prefix<SB_, 7><<<dim3(ND_ / 256), b256, 0, stream>>>(
            h_a, h_s, alpha, P, Q0, S1, out_ha_final, out_hs_final);
        k5_fb<<<dim3(SNDB_ / 256), b256, 0, stream>>>(x, alpha, P, Q0, out);
    }
}